// Round 5
// baseline (305.852 us; speedup 1.0000x reference)
//
#include <hip/hip_runtime.h>
#include <hip/hip_bf16.h>

#define MB_ROWS  8192            // 16 * 512
#define N_LINES  12
#define SCALE    (0.01f / 512.0f)
#define FL_CONST 170.0f          // PROBE_CTS * FL_RATIO * SA_ADJ * SA_THETA
#define TAREA    3072            // per-elem LDS tile (floats); >= worst-case bbox area

// Block = 8 output rows (one channel) x 512 samples in 8 chunks of 64.
// Per chunk: stage the source bounding box of the 8x64 output tile into LDS
// (coalesced row loads), then wave w computes row w's 64 samples entirely
// from LDS: bilinear gather (LDS), wave-local scan, exp, fl accumulation.
// No cross-wave redistribution at all. Row stride in LDS padded to 64 so
// gather bank = x mod 32 -> ~2-way conflicts (free).
__global__ __launch_bounds__(512, 4) void fused_fl_kernel(
    const float* __restrict__ xp,       // (5, 16, 512, 512)
    const float* __restrict__ attCS,    // (5,)
    const float* __restrict__ dfl,      // (12,)
    const float* __restrict__ theta_p,  // (1,)
    const int*   __restrict__ lidx,     // (12,)
    float*       __restrict__ out)      // fl_sig (12*8192) ++ transmission (8192)
{
    const int bid = blockIdx.x;
    const int t   = bid >> 3;
    const int c   = (bid & 7) + 8 * (t >> 6);   // channel, XCD-affine
    const int g   = t & 63;
    const int irow0 = g << 3;

    const int tid  = threadIdx.x;
    const int lane = tid & 63;
    const int w    = tid >> 6;        // wave id = row within group

    const float theta = theta_p[0];
    const float cs = cosf(theta);
    const float sn = sinf(theta);

    const int irow = irow0 + w;
    const float gy  = (2.0f * (float)irow + 1.0f) * (1.0f / 512.0f) - 1.0f;
    // row-group gy extremes (uniform)
    const float gya = (2.0f * (float)irow0       + 1.0f) * (1.0f / 512.0f) - 1.0f;
    const float gyb = (2.0f * (float)(irow0 + 7) + 1.0f) * (1.0f / 512.0f) - 1.0f;

    const size_t estride = (size_t)16 * 512 * 512;
    const float* base = xp + (size_t)c * (512 * 512);

    const float a0 = attCS[0], a1 = attCS[1], a2 = attCS[2], a3 = attCS[3], a4 = attCS[4];

    __shared__ float s_tile[5 * TAREA];   // 61440 B -> 2 blocks/CU

    float se0 = 0.f, se1 = 0.f, se2 = 0.f, se3 = 0.f, se4 = 0.f;
    float carry = 0.f;

    for (int k = 0; k < 8; ++k) {
        // ---- uniform bbox of this chunk's source coords (corners of affine) ----
        const float gxa = (2.0f * (float)(k << 6)        + 1.0f) * (1.0f / 512.0f) - 1.0f;
        const float gxb = (2.0f * (float)((k << 6) + 63) + 1.0f) * (1.0f / 512.0f) - 1.0f;

        const float xi00 = cs * gxa - sn * gya, xi01 = cs * gxa - sn * gyb;
        const float xi10 = cs * gxb - sn * gya, xi11 = cs * gxb - sn * gyb;
        const float yi00 = sn * gxa + cs * gya, yi01 = sn * gxa + cs * gyb;
        const float yi10 = sn * gxb + cs * gya, yi11 = sn * gxb + cs * gyb;

        float xmn = fminf(fminf(xi00, xi01), fminf(xi10, xi11));
        float xmx = fmaxf(fmaxf(xi00, xi01), fmaxf(xi10, xi11));
        float ymn = fminf(fminf(yi00, yi01), fminf(yi10, yi11));
        float ymx = fmaxf(fmaxf(yi00, yi01), fmaxf(yi10, yi11));

        float ixmn = fminf(fmaxf(((xmn + 1.0f) * 512.0f - 1.0f) * 0.5f, 0.0f), 511.0f);
        float ixmx = fminf(fmaxf(((xmx + 1.0f) * 512.0f - 1.0f) * 0.5f, 0.0f), 511.0f);
        float iymn = fminf(fmaxf(((ymn + 1.0f) * 512.0f - 1.0f) * 0.5f, 0.0f), 511.0f);
        float iymx = fminf(fmaxf(((ymx + 1.0f) * 512.0f - 1.0f) * 0.5f, 0.0f), 511.0f);

        const int bbx0 = (int)floorf(ixmn);
        const int bbx1 = min((int)floorf(ixmx) + 2, 511);   // +1 bilinear, +1 rounding safety
        const int bby0 = (int)floorf(iymn);
        const int bby1 = min((int)floorf(iymx) + 2, 511);
        const int W = bbx1 - bbx0 + 1;                       // <= 62 at theta=pi/6
        int H = bby1 - bby0 + 1;                             // <= 41 at theta=pi/6

        // fast path: fixed row stride 64 (bank = x mod 32). Generic-theta fallback.
        const int fast = (W <= 64 && H <= 48);
        const int Wp = fast ? 64 : W;
        int maxH = fast ? 48 : (TAREA / Wp);
        if (H > maxH) H = maxH;   // defensive; never triggers for valid theta

        __syncthreads();   // previous chunk's LDS reads complete

        // ---- stage: 5 planes x bbox rows, coalesced ----
#pragma unroll
        for (int e = 0; e < 5; ++e) {
            const float* plane = base + (size_t)e * estride;
            float* tile = &s_tile[e * TAREA];
            for (int yy = w; yy < H; yy += 8) {
                const float* src = plane + (bby0 + yy) * 512 + bbx0;
                float* dst = tile + yy * Wp;
                if (lane < W) dst[lane] = src[lane];
                if (64 + lane < W) dst[64 + lane] = src[64 + lane];  // W<=128 tail (dead at pi/6)
            }
        }
        __syncthreads();

        // ---- compute: wave w handles row irow, samples s = 64k + lane ----
        const int s = (k << 6) + lane;
        const float gx = (2.0f * (float)s + 1.0f) * (1.0f / 512.0f) - 1.0f;
        const float x_in = cs * gx - sn * gy;
        const float y_in = sn * gx + cs * gy;
        float ix = ((x_in + 1.0f) * 512.0f - 1.0f) * 0.5f;
        float iy = ((y_in + 1.0f) * 512.0f - 1.0f) * 0.5f;
        ix = fminf(fmaxf(ix, 0.0f), 511.0f);
        iy = fminf(fmaxf(iy, 0.0f), 511.0f);

        const float x0f = floorf(ix);
        const float y0f = floorf(iy);
        const float wx = ix - x0f;
        const float wy = iy - y0f;
        const int x0 = (int)x0f;
        const int y0 = (int)y0f;
        const int x1 = min(x0 + 1, 511);
        const int y1 = min(y0 + 1, 511);

        const float w00 = (1.0f - wx) * (1.0f - wy);
        const float w01 = wx * (1.0f - wy);
        const float w10 = (1.0f - wx) * wy;
        const float w11 = wx * wy;

        const int ly0 = (y0 - bby0) * Wp;
        const int ly1 = (y1 - bby0) * Wp;
        const int lx0 = x0 - bbx0;
        const int lx1 = x1 - bbx0;
        const int o00 = ly0 + lx0, o01 = ly0 + lx1;
        const int o10 = ly1 + lx0, o11 = ly1 + lx1;

        float cv0, cv1, cv2, cv3, cv4;
        {
            const float* tp = s_tile;
            cv0 = w00 * tp[o00] + w01 * tp[o01] + w10 * tp[o10] + w11 * tp[o11];
            tp += TAREA;
            cv1 = w00 * tp[o00] + w01 * tp[o01] + w10 * tp[o10] + w11 * tp[o11];
            tp += TAREA;
            cv2 = w00 * tp[o00] + w01 * tp[o01] + w10 * tp[o10] + w11 * tp[o11];
            tp += TAREA;
            cv3 = w00 * tp[o00] + w01 * tp[o01] + w10 * tp[o10] + w11 * tp[o11];
            tp += TAREA;
            cv4 = w00 * tp[o00] + w01 * tp[o01] + w10 * tp[o10] + w11 * tp[o11];
        }

        float lac = a0 * cv0;
        lac = fmaf(a1, cv1, lac);
        lac = fmaf(a2, cv2, lac);
        lac = fmaf(a3, cv3, lac);
        lac = fmaf(a4, cv4, lac);

        // ---- wave-local inclusive scan over the 64 samples ----
        float v = lac;
#pragma unroll
        for (int off = 1; off < 64; off <<= 1) {
            float n = __shfl_up(v, off, 64);
            if (lane >= off) v += n;
        }
        const float tot  = __shfl(v, 63, 64);
        const float excl = carry + v - lac;
        const float att  = __expf(-excl * SCALE);
        carry += tot;

        se0 = fmaf(att, cv0, se0);
        se1 = fmaf(att, cv1, se1);
        se2 = fmaf(att, cv2, se2);
        se3 = fmaf(att, cv3, se3);
        se4 = fmaf(att, cv4, se4);
    }

    // ---- epilogue: wave-local, no barriers ----
#pragma unroll
    for (int off = 32; off > 0; off >>= 1) {
        se0 += __shfl_down(se0, off, 64);
        se1 += __shfl_down(se1, off, 64);
        se2 += __shfl_down(se2, off, 64);
        se3 += __shfl_down(se3, off, 64);
        se4 += __shfl_down(se4, off, 64);
    }
    const float S0 = __shfl(se0, 0, 64);
    const float S1 = __shfl(se1, 0, 64);
    const float S2 = __shfl(se2, 0, 64);
    const float S3 = __shfl(se3, 0, 64);
    const float S4 = __shfl(se4, 0, 64);

    const size_t b = (size_t)c * 512 + irow;
    if (lane == 0) {
        out[(size_t)N_LINES * MB_ROWS + b] = carry * SCALE;
    }
    if (lane < N_LINES) {
        const int li = lidx[lane];
        float Ssel = S0;
        Ssel = (li == 1) ? S1 : Ssel;
        Ssel = (li == 2) ? S2 : Ssel;
        Ssel = (li == 3) ? S3 : Ssel;
        Ssel = (li == 4) ? S4 : Ssel;
        out[(size_t)lane * MB_ROWS + b] = FL_CONST * dfl[lane] * Ssel;
    }
}

extern "C" void kernel_launch(void* const* d_in, const int* in_sizes, int n_in,
                              void* d_out, int out_size, void* d_ws, size_t ws_size,
                              hipStream_t stream) {
    const float* xp    = (const float*)d_in[0];
    const float* attCS = (const float*)d_in[1];
    const float* dfl   = (const float*)d_in[2];
    const float* theta = (const float*)d_in[3];
    const int*   lidx  = (const int*)d_in[4];
    float* out = (float*)d_out;

    fused_fl_kernel<<<MB_ROWS / 8, 512, 0, stream>>>(xp, attCS, dfl, theta, lidx, out);
}

// Round 7
// 187.209 us; speedup vs baseline: 1.6337x; 1.6337x over previous
//
#include <hip/hip_runtime.h>
#include <hip/hip_bf16.h>

#define MB_ROWS  8192            // 16 * 512
#define N_LINES  12
#define SCALE    (0.01f / 512.0f)
#define FL_CONST 170.0f          // PROBE_CTS * FL_RATIO * SA_ADJ * SA_THETA

// Block = 8 output rows (one channel) x 512 samples in 8 chunks of 64.
// Gather phase: thread (r=tid&7, sc=tid>>3) gathers sample s=64k+sc of row
// irow0+r straight from global (wave = 8x8 output patch -> ~19 cache lines
// per gather instruction). It writes cv0..cv4 + lac (6 floats) into a
// double-buffered LDS slab. ONE barrier. Scan phase: wave w owns row w:
// reads its 64 lanes' 6 values (2-way banks = free), wave-local shfl scan,
// exp, and fl-partial accumulation in registers. No second barrier, no att
// round-trip, barrier-free wave-local epilogue.
__global__ __launch_bounds__(512) void fused_fl_kernel(
    const float* __restrict__ xp,       // (5, 16, 512, 512)
    const float* __restrict__ attCS,    // (5,)
    const float* __restrict__ dfl,      // (12,)
    const float* __restrict__ theta_p,  // (1,)
    const int*   __restrict__ lidx,     // (12,)
    float*       __restrict__ out)      // fl_sig (12*8192) ++ transmission (8192)
{
    const int bid = blockIdx.x;
    const int t   = bid >> 3;
    const int c   = (bid & 7) + 8 * (t >> 6);   // channel, XCD-affine
    const int g   = t & 63;
    const int irow0 = g << 3;

    const int tid  = threadIdx.x;
    const int r    = tid & 7;    // gather row within group
    const int sc   = tid >> 3;   // gather column slot 0..63
    const int lane = tid & 63;
    const int w    = tid >> 6;   // wave id; wave w owns row irow0+w

    const float theta = theta_p[0];
    const float cs = cosf(theta);
    const float sn = sinf(theta);

    const float gyr = (2.0f * (float)(irow0 + r) + 1.0f) * (1.0f / 512.0f) - 1.0f;

    const size_t estride = (size_t)16 * 512 * 512;
    const float* base = xp + (size_t)c * (512 * 512);

    const float a0 = attCS[0], a1 = attCS[1], a2 = attCS[2], a3 = attCS[3], a4 = attCS[4];

    // [buf][field][row][slot(+pad)]; fields 0..4 = conc, 5 = lac. 27648 B.
    __shared__ float s_x[2][6][8][72];

    float se0 = 0.f, se1 = 0.f, se2 = 0.f, se3 = 0.f, se4 = 0.f;
    float carry = 0.f;

    for (int k = 0; k < 8; ++k) {
        const int buf = k & 1;

        // ---- gather phase (patch mapping) ----
        {
            const int s = sc + (k << 6);
            const float gx = (2.0f * (float)s + 1.0f) * (1.0f / 512.0f) - 1.0f;
            const float x_in = cs * gx - sn * gyr;
            const float y_in = sn * gx + cs * gyr;
            float ix = ((x_in + 1.0f) * 512.0f - 1.0f) * 0.5f;
            float iy = ((y_in + 1.0f) * 512.0f - 1.0f) * 0.5f;
            ix = fminf(fmaxf(ix, 0.0f), 511.0f);
            iy = fminf(fmaxf(iy, 0.0f), 511.0f);

            const float x0f = floorf(ix);
            const float y0f = floorf(iy);
            const float wx = ix - x0f;
            const float wy = iy - y0f;
            const int x0 = (int)x0f;
            const int y0 = (int)y0f;
            const int x1 = min(x0 + 1, 511);
            const int y1 = min(y0 + 1, 511);

            const float w00 = (1.0f - wx) * (1.0f - wy);
            const float w01 = wx * (1.0f - wy);
            const float w10 = (1.0f - wx) * wy;
            const float w11 = wx * wy;

            const int o00 = y0 * 512 + x0;
            const int o01 = y0 * 512 + x1;
            const int o10 = y1 * 512 + x0;
            const int o11 = y1 * 512 + x1;

            float cv0, cv1, cv2, cv3, cv4;
            {
                const float* p = base;
                cv0 = w00 * p[o00] + w01 * p[o01] + w10 * p[o10] + w11 * p[o11];
                p += estride;
                cv1 = w00 * p[o00] + w01 * p[o01] + w10 * p[o10] + w11 * p[o11];
                p += estride;
                cv2 = w00 * p[o00] + w01 * p[o01] + w10 * p[o10] + w11 * p[o11];
                p += estride;
                cv3 = w00 * p[o00] + w01 * p[o01] + w10 * p[o10] + w11 * p[o11];
                p += estride;
                cv4 = w00 * p[o00] + w01 * p[o01] + w10 * p[o10] + w11 * p[o11];
            }
            float lac = a0 * cv0;
            lac = fmaf(a1, cv1, lac);
            lac = fmaf(a2, cv2, lac);
            lac = fmaf(a3, cv3, lac);
            lac = fmaf(a4, cv4, lac);

            s_x[buf][0][r][sc] = cv0;
            s_x[buf][1][r][sc] = cv1;
            s_x[buf][2][r][sc] = cv2;
            s_x[buf][3][r][sc] = cv3;
            s_x[buf][4][r][sc] = cv4;
            s_x[buf][5][r][sc] = lac;
        }

        __syncthreads();   // single barrier per chunk (double-buffered slab)

        // ---- scan + accumulate phase: wave w owns row irow0+w ----
        {
            const float lv = s_x[buf][5][w][lane];
            float v = lv;
#pragma unroll
            for (int off = 1; off < 64; off <<= 1) {
                float n = __shfl_up(v, off, 64);
                if (lane >= off) v += n;
            }
            const float tot  = __shfl(v, 63, 64);
            const float excl = carry + v - lv;
            const float att  = __expf(-excl * SCALE);
            carry += tot;

            const float d0 = s_x[buf][0][w][lane];
            const float d1 = s_x[buf][1][w][lane];
            const float d2 = s_x[buf][2][w][lane];
            const float d3 = s_x[buf][3][w][lane];
            const float d4 = s_x[buf][4][w][lane];
            se0 = fmaf(att, d0, se0);
            se1 = fmaf(att, d1, se1);
            se2 = fmaf(att, d2, se2);
            se3 = fmaf(att, d3, se3);
            se4 = fmaf(att, d4, se4);
        }
    }

    // ---- epilogue: wave-local, no barriers ----
#pragma unroll
    for (int off = 32; off > 0; off >>= 1) {
        se0 += __shfl_down(se0, off, 64);
        se1 += __shfl_down(se1, off, 64);
        se2 += __shfl_down(se2, off, 64);
        se3 += __shfl_down(se3, off, 64);
        se4 += __shfl_down(se4, off, 64);
    }
    const float S0 = __shfl(se0, 0, 64);
    const float S1 = __shfl(se1, 0, 64);
    const float S2 = __shfl(se2, 0, 64);
    const float S3 = __shfl(se3, 0, 64);
    const float S4 = __shfl(se4, 0, 64);

    const size_t b = (size_t)c * 512 + irow0 + w;
    if (lane == 0) {
        out[(size_t)N_LINES * MB_ROWS + b] = carry * SCALE;
    }
    if (lane < N_LINES) {
        const int li = lidx[lane];
        float Ssel = S0;
        Ssel = (li == 1) ? S1 : Ssel;
        Ssel = (li == 2) ? S2 : Ssel;
        Ssel = (li == 3) ? S3 : Ssel;
        Ssel = (li == 4) ? S4 : Ssel;
        out[(size_t)lane * MB_ROWS + b] = FL_CONST * dfl[lane] * Ssel;
    }
}

extern "C" void kernel_launch(void* const* d_in, const int* in_sizes, int n_in,
                              void* d_out, int out_size, void* d_ws, size_t ws_size,
                              hipStream_t stream) {
    const float* xp    = (const float*)d_in[0];
    const float* attCS = (const float*)d_in[1];
    const float* dfl   = (const float*)d_in[2];
    const float* theta = (const float*)d_in[3];
    const int*   lidx  = (const int*)d_in[4];
    float* out = (float*)d_out;

    fused_fl_kernel<<<MB_ROWS / 8, 512, 0, stream>>>(xp, attCS, dfl, theta, lidx, out);
}

// Round 8
// 171.169 us; speedup vs baseline: 1.7868x; 1.0937x over previous
//
#include <hip/hip_runtime.h>
#include <hip/hip_bf16.h>

#define MB_ROWS  8192            // 16 * 512
#define N_LINES  12
#define SCALE    (0.01f / 512.0f)
#define FL_CONST 170.0f          // PROBE_CTS * FL_RATIO * SA_ADJ * SA_THETA

// 8-byte (possibly 4B-aligned) load carrying both x-taps of one source row.
// gfx9+ global memory supports unaligned vector access in HW; if the
// compiler chooses to split, we land back at R7's 2x dword behavior.
struct __attribute__((packed, aligned(4))) F2 { float x, y; };

// Block = 8 output rows (one channel) x 512 samples in 8 chunks of 64.
// Gather: thread (r=tid&7, sc=tid>>3) -> wave covers an 8x8 output patch.
// Per (elem, y-tap) ONE 8B load carries both x-taps (x0,x0+1): 10 gather
// instructions per chunk instead of 20 -> ~2x fewer TA cache-line walks
// (the x-taps shared the same line ~94% of the time anyway).
// Values flow through a double-buffered LDS slab (one barrier per chunk);
// wave w then owns row irow0+w: wave-local scan, exp, fl accumulation.
__global__ __launch_bounds__(512) void fused_fl_kernel(
    const float* __restrict__ xp,       // (5, 16, 512, 512)
    const float* __restrict__ attCS,    // (5,)
    const float* __restrict__ dfl,      // (12,)
    const float* __restrict__ theta_p,  // (1,)
    const int*   __restrict__ lidx,     // (12,)
    float*       __restrict__ out)      // fl_sig (12*8192) ++ transmission (8192)
{
    const int bid = blockIdx.x;
    const int t   = bid >> 3;
    const int c   = (bid & 7) + 8 * (t >> 6);   // channel, XCD-affine
    const int g   = t & 63;
    const int irow0 = g << 3;

    const int tid  = threadIdx.x;
    const int r    = tid & 7;    // gather row within group
    const int sc   = tid >> 3;   // gather column slot 0..63
    const int lane = tid & 63;
    const int w    = tid >> 6;   // wave id; wave w owns row irow0+w

    const float theta = theta_p[0];
    const float cs = cosf(theta);
    const float sn = sinf(theta);

    const float gyr = (2.0f * (float)(irow0 + r) + 1.0f) * (1.0f / 512.0f) - 1.0f;

    const size_t estride = (size_t)16 * 512 * 512;
    const float* base = xp + (size_t)c * (512 * 512);

    const float a0 = attCS[0], a1 = attCS[1], a2 = attCS[2], a3 = attCS[3], a4 = attCS[4];

    // [buf][field][row][slot(+pad)]; fields 0..4 = conc, 5 = lac. 27648 B.
    __shared__ float s_x[2][6][8][72];

    float se0 = 0.f, se1 = 0.f, se2 = 0.f, se3 = 0.f, se4 = 0.f;
    float carry = 0.f;

    for (int k = 0; k < 8; ++k) {
        const int buf = k & 1;

        // ---- gather phase (patch mapping, paired x-taps) ----
        {
            const int s = sc + (k << 6);
            const float gx = (2.0f * (float)s + 1.0f) * (1.0f / 512.0f) - 1.0f;
            const float x_in = cs * gx - sn * gyr;
            const float y_in = sn * gx + cs * gyr;
            float ix = ((x_in + 1.0f) * 512.0f - 1.0f) * 0.5f;
            float iy = ((y_in + 1.0f) * 512.0f - 1.0f) * 0.5f;
            ix = fminf(fmaxf(ix, 0.0f), 511.0f);
            iy = fminf(fmaxf(iy, 0.0f), 511.0f);

            const float x0f = floorf(ix);
            const float y0f = floorf(iy);
            const float wx = ix - x0f;
            const float wy = iy - y0f;
            const int x0 = (int)x0f;
            const int y0 = (int)y0f;
            const int y1 = min(y0 + 1, 511);

            const bool edge = (x0 >= 511);
            const int  xL   = edge ? 510 : x0;

            const float w1y0 = wx * (1.0f - wy);   // weight for (y0, x0+1)
            const float w1y1 = wx * wy;            // weight for (y1, x0+1)
            const float w0y0 = (1.0f - wx) * (1.0f - wy);
            const float w0y1 = (1.0f - wx) * wy;

            const int oA = y0 * 512 + xL;          // row y0, both x-taps
            const int oB = y1 * 512 + xL;          // row y1, both x-taps

            float cv[5];
            const float* p = base;
#pragma unroll
            for (int e = 0; e < 5; ++e) {
                const F2 pa = *(const F2*)(p + oA);
                const F2 pb = *(const F2*)(p + oB);
                const float vA0 = edge ? pa.y : pa.x;   // (y0, x0)
                const float vB0 = edge ? pb.y : pb.x;   // (y1, x0)
                // (y0/y1, x0+1) == pa.y/pb.y (exact at edge too, where wx=0)
                float acc = w0y0 * vA0;
                acc = fmaf(w1y0, pa.y, acc);
                acc = fmaf(w0y1, vB0, acc);
                acc = fmaf(w1y1, pb.y, acc);
                cv[e] = acc;
                p += estride;
            }

            float lac = a0 * cv[0];
            lac = fmaf(a1, cv[1], lac);
            lac = fmaf(a2, cv[2], lac);
            lac = fmaf(a3, cv[3], lac);
            lac = fmaf(a4, cv[4], lac);

            s_x[buf][0][r][sc] = cv[0];
            s_x[buf][1][r][sc] = cv[1];
            s_x[buf][2][r][sc] = cv[2];
            s_x[buf][3][r][sc] = cv[3];
            s_x[buf][4][r][sc] = cv[4];
            s_x[buf][5][r][sc] = lac;
        }

        __syncthreads();   // single barrier per chunk (double-buffered slab)

        // ---- scan + accumulate phase: wave w owns row irow0+w ----
        {
            const float lv = s_x[buf][5][w][lane];
            float v = lv;
#pragma unroll
            for (int off = 1; off < 64; off <<= 1) {
                float n = __shfl_up(v, off, 64);
                if (lane >= off) v += n;
            }
            const float tot  = __shfl(v, 63, 64);
            const float excl = carry + v - lv;
            const float att  = __expf(-excl * SCALE);
            carry += tot;

            const float d0 = s_x[buf][0][w][lane];
            const float d1 = s_x[buf][1][w][lane];
            const float d2 = s_x[buf][2][w][lane];
            const float d3 = s_x[buf][3][w][lane];
            const float d4 = s_x[buf][4][w][lane];
            se0 = fmaf(att, d0, se0);
            se1 = fmaf(att, d1, se1);
            se2 = fmaf(att, d2, se2);
            se3 = fmaf(att, d3, se3);
            se4 = fmaf(att, d4, se4);
        }
    }

    // ---- epilogue: wave-local, no barriers ----
#pragma unroll
    for (int off = 32; off > 0; off >>= 1) {
        se0 += __shfl_down(se0, off, 64);
        se1 += __shfl_down(se1, off, 64);
        se2 += __shfl_down(se2, off, 64);
        se3 += __shfl_down(se3, off, 64);
        se4 += __shfl_down(se4, off, 64);
    }
    const float S0 = __shfl(se0, 0, 64);
    const float S1 = __shfl(se1, 0, 64);
    const float S2 = __shfl(se2, 0, 64);
    const float S3 = __shfl(se3, 0, 64);
    const float S4 = __shfl(se4, 0, 64);

    const size_t b = (size_t)c * 512 + irow0 + w;
    if (lane == 0) {
        out[(size_t)N_LINES * MB_ROWS + b] = carry * SCALE;
    }
    if (lane < N_LINES) {
        const int li = lidx[lane];
        float Ssel = S0;
        Ssel = (li == 1) ? S1 : Ssel;
        Ssel = (li == 2) ? S2 : Ssel;
        Ssel = (li == 3) ? S3 : Ssel;
        Ssel = (li == 4) ? S4 : Ssel;
        out[(size_t)lane * MB_ROWS + b] = FL_CONST * dfl[lane] * Ssel;
    }
}

extern "C" void kernel_launch(void* const* d_in, const int* in_sizes, int n_in,
                              void* d_out, int out_size, void* d_ws, size_t ws_size,
                              hipStream_t stream) {
    const float* xp    = (const float*)d_in[0];
    const float* attCS = (const float*)d_in[1];
    const float* dfl   = (const float*)d_in[2];
    const float* theta = (const float*)d_in[3];
    const int*   lidx  = (const int*)d_in[4];
    float* out = (float*)d_out;

    fused_fl_kernel<<<MB_ROWS / 8, 512, 0, stream>>>(xp, attCS, dfl, theta, lidx, out);
}